// Round 7
// baseline (3269.905 us; speedup 1.0000x reference)
//
#include <hip/hip_runtime.h>
#include <math.h>

typedef unsigned short ushort;
typedef unsigned int uint;
typedef __bf16 bf16x8 __attribute__((ext_vector_type(8)));
typedef float f32x4 __attribute__((ext_vector_type(4)));

// Problem constants
#define ZS    128
#define KS    256
#define HS    512
#define BATCH 512
#define TT    32
#define MM    33
#define HOFF  272      // k: 0..255 key_r, 256 conf, 257..271 pad, 272..783 h, 784..799 pad
#define NBLK  256
// packed A: [mt(32)][s(25)][hi/lo(2)][lane(64)][e(8)]  (bf16 fragment order)
#define APK   819200
// gates B: [G(16)][T(9)][s(25)][hi/lo(2)][lane(64)][e(8)]
#define GP    (16*9*25*2*512)
// encoder B: [T(8)][s(32)][hi/lo(2)][lane(64)][e(8)]
#define EP    (8*32*2*512)

static __device__ __forceinline__ float sigf(float x) { return 1.f / (1.f + expf(-x)); }
static __device__ __forceinline__ float bf2f(ushort u) { return __uint_as_float((uint)u << 16); }
static __device__ __forceinline__ ushort f2hi(float v) { return (ushort)(__float_as_uint(v) >> 16); }
static __device__ __forceinline__ ushort f2lo(float v) {
    uint u = __float_as_uint(v);
    float lo = v - __uint_as_float(u & 0xFFFF0000u);
    return (ushort)(__float_as_uint(lo) >> 16);
}

// Device-scope grid barrier: monotonic arrival counter (no generation race;
// stale reads only lengthen the spin, never shorten it). cnt zeroed per call.
static __device__ __forceinline__ void gbar(uint* cnt) {
    __syncthreads();
    if (threadIdx.x == 0) {
        __threadfence();   // release: h/key_r/Mk stores -> L3
        uint old = __hip_atomic_fetch_add(cnt, 1u, __ATOMIC_RELAXED, __HIP_MEMORY_SCOPE_AGENT);
        uint target = (old / NBLK + 1u) * NBLK;
        while (__hip_atomic_load(cnt, __ATOMIC_RELAXED, __HIP_MEMORY_SCOPE_AGENT) < target)
            __builtin_amdgcn_s_sleep(2);
        __threadfence();   // acquire: invalidate L1/L2 before reading peers' data
    }
    __syncthreads();
}

// ---------------------------------------------------------------------------
// Weight prep into MFMA-fragment-packed streams (same layout as R6).
// ---------------------------------------------------------------------------
__global__ void prep_w(const float* __restrict__ W_ih, const float* __restrict__ W_hh,
                       const float* __restrict__ W_key, const float* __restrict__ b_ih,
                       const float* __restrict__ b_hh, const float* __restrict__ b_key,
                       const float* __restrict__ W_enc,
                       ushort* __restrict__ Wpk, ushort* __restrict__ Epk,
                       float* __restrict__ biasPk)
{
    int idx = blockIdx.x * 256 + threadIdx.x;
    if (idx < GP) {
        int e = idx & 7, r = idx >> 3;
        int l = r & 63; r >>= 6;
        int h = r & 1;  r >>= 1;
        int s = r % 25; r /= 25;
        int T = r % 9,  G = r / 9;
        int k = s * 32 + ((l >> 4) << 3) + e;
        int c16 = l & 15;
        float v = 0.f;
        if (T < 8) {
            int unit = G * 32 + (T >> 2) * 16 + c16;
            int wrow = (T & 3) * 512 + unit;
            if (k < 257) v = W_ih[wrow * 257 + k];
            else if (k >= HOFF && k < HOFF + 512) v = W_hh[wrow * 512 + (k - HOFF)];
        } else {
            int krow = G * 16 + c16;
            if (k >= HOFF && k < HOFF + 512) v = W_key[krow * 512 + (k - HOFF)];
        }
        Wpk[idx] = h ? f2lo(v) : f2hi(v);
    } else if (idx < GP + EP) {
        int q = idx - GP;
        int e = q & 7, r = q >> 3;
        int l = r & 63; r >>= 6;
        int h = r & 1;  r >>= 1;
        int s = r & 31; int T = r >> 5;
        int k = s * 32 + ((l >> 4) << 3) + e;
        int n = T * 16 + (l & 15);
        float v = W_enc[k * 128 + n];
        Epk[q] = h ? f2lo(v) : f2hi(v);
    } else if (idx < GP + EP + 2304) {
        int q = idx - GP - EP;
        int G = q / 144, rr = q - G * 144, T = rr >> 4, c16 = rr & 15;
        float bv;
        if (T < 8) {
            int unit = G * 32 + (T >> 2) * 16 + c16;
            int wrow = (T & 3) * 512 + unit;
            bv = b_ih[wrow] + b_hh[wrow];
        } else bv = b_key[G * 16 + c16];
        biasPk[q] = bv;
    }
}

// ---------------------------------------------------------------------------
// Encoder GEMM: 512 blocks (2/CU) x 32 rows. Register-stream, 3-phase
// prefetch, no LDS. A fp32 from HBM split hi/lo in-lane.
// ---------------------------------------------------------------------------
__global__ __launch_bounds__(256)
void enc_k(const float* __restrict__ x, const ushort* __restrict__ Epk,
           float* __restrict__ z_pad)
{
    const int flat = blockIdx.x, tid = threadIdx.x;
    const int l = tid & 63, w = tid >> 6, wm = w >> 1, wn = w & 1;
    const int c16 = l & 15, kq = l >> 4;
    const int mtile = flat * 2 + wm;

    const float* Arow = x + (size_t)(mtile * 16 + c16) * 1024 + kq * 8;
    const ushort* Bb[4];
#pragma unroll
    for (int ti = 0; ti < 4; ti++)
        Bb[ti] = Epk + (size_t)(wn * 4 + ti) * 32768 + l * 8;

    f32x4 acc[4];
#pragma unroll
    for (int ti = 0; ti < 4; ti++) acc[ti] = (f32x4){0.f, 0.f, 0.f, 0.f};

    float4 af[3][2];
    bf16x8 bb[3][4][2];
    auto LD = [&](int s, int ph) {
        af[ph][0] = *(const float4*)(Arow + s * 32);
        af[ph][1] = *(const float4*)(Arow + s * 32 + 4);
#pragma unroll
        for (int ti = 0; ti < 4; ti++) {
            bb[ph][ti][0] = *(const bf16x8*)(Bb[ti] + (s * 2 + 0) * 512);
            bb[ph][ti][1] = *(const bf16x8*)(Bb[ti] + (s * 2 + 1) * 512);
        }
    };

    LD(0, 0); LD(1, 1);
#pragma unroll
    for (int s = 0; s < 32; s++) {
        const int ph = s % 3;
        if (s + 2 < 32) LD(s + 2, (s + 2) % 3);
        float fv[8];
        *(float4*)&fv[0] = af[ph][0];
        *(float4*)&fv[4] = af[ph][1];
        ushort hi8[8] __attribute__((aligned(16)));
        ushort lo8[8] __attribute__((aligned(16)));
#pragma unroll
        for (int e2 = 0; e2 < 8; e2++) { hi8[e2] = f2hi(fv[e2]); lo8[e2] = f2lo(fv[e2]); }
        bf16x8 ah = *(bf16x8*)hi8, al = *(bf16x8*)lo8;
#pragma unroll
        for (int ti = 0; ti < 4; ti++) {
            acc[ti] = __builtin_amdgcn_mfma_f32_16x16x32_bf16(ah, bb[ph][ti][0], acc[ti], 0, 0, 0);
            acc[ti] = __builtin_amdgcn_mfma_f32_16x16x32_bf16(ah, bb[ph][ti][1], acc[ti], 0, 0, 0);
            acc[ti] = __builtin_amdgcn_mfma_f32_16x16x32_bf16(al, bb[ph][ti][0], acc[ti], 0, 0, 0);
        }
    }
    const int crow = (l >> 4) << 2;
#pragma unroll
    for (int ti = 0; ti < 4; ti++) {
        int z = (wn * 4 + ti) * 16 + c16;
#pragma unroll
        for (int rr = 0; rr < 4; rr++) {
            int m = mtile * 16 + crow + rr;
            z_pad[(size_t)(m >> 5) * (MM * ZS) + (m & 31) * ZS + z] = acc[ti][rr];
        }
    }
}

// ---------------------------------------------------------------------------
// PERSISTENT loop kernel: 256 blocks x 256 thr (1/CU, co-resident).
// Phase 0 (block-local): context-norm + attention scores for its 2 batch
// rows -> watt/wc kept in LDS for the whole kernel.
// Then for t=0..32: gates GEMM+LSTM cell (c-state in registers!) -> barrier
// -> post (g-gate + attention read -> key_r(t+1)) -> barrier. Finally y.
// ---------------------------------------------------------------------------
__global__ __launch_bounds__(256, 1)
void loop_k(const float* __restrict__ z_pad, const ushort* __restrict__ Wpk,
            const float* __restrict__ biasPk, float* __restrict__ Mk,
            ushort* __restrict__ buf0, ushort* __restrict__ buf1,
            const float* __restrict__ W_g, const float* __restrict__ b_g,
            const float* __restrict__ cg_p, const float* __restrict__ cb_p,
            const float* __restrict__ W_y, const float* __restrict__ b_y,
            const float* __restrict__ gamma, const float* __restrict__ beta,
            float* __restrict__ out, uint* __restrict__ bar)
{
    __shared__ float zs[2][33 * 133];   // normed z, stride 133 (conflict-free)
    __shared__ float wl[2][33 * 33];    // row t>=1: watt[t][m]; row 0: wc[t]
    __shared__ float red[256];
    __shared__ float gsh;

    const int flat = blockIdx.x, tid = threadIdx.x;
    const int l = tid & 63, w = tid >> 6, wm = w >> 1, wn = w & 1;
    const int G = (flat & 7) * 2 + ((flat >> 3) & 1);   // same-G blocks same XCD
    const int my = flat >> 4;
    const int c16 = l & 15;

    // ---- phase 0: norm + scores for rows 2*flat, 2*flat+1 (block-local)
    {
        int rr = tid >> 7, zc = tid & 127;
        int b = flat * 2 + rr;
        const float* zb = z_pad + (size_t)b * (MM * ZS);
        float s = 0.f, s2 = 0.f;
        for (int t = 0; t < TT; t++) { float v = zb[t * ZS + zc]; s += v; s2 += v * v; }
        float mu = s * (1.f / 32.f);
        float var = s2 * (1.f / 32.f) - mu * mu;
        float rstd = 1.f / sqrtf(var + 1e-8f);
        float ga = gamma[zc], be = beta[zc];
        for (int t = 0; t < TT; t++)
            zs[rr][t * 133 + zc] = (zb[t * ZS + zc] - mu) * rstd * ga + be;
        zs[rr][32 * 133 + zc] = 0.f;
        __syncthreads();
        float cg = cg_p[0], cb = cb_p[0];
        int rw = w >> 1;
        for (int t = 1 + (w & 1); t <= 32; t += 2) {
            int m = l;
            float sc = -3.0e38f;
            if (m < t) {
                const float* zt = &zs[rw][t * 133];
                const float* zm = &zs[rw][m * 133];
                float a = 0.f;
#pragma unroll 8
                for (int k = 0; k < ZS; k++) a += zt[k] * zm[k];
                sc = a;
            }
            float mx = sc;
            for (int off = 1; off < 64; off <<= 1) mx = fmaxf(mx, __shfl_xor(mx, off));
            float e = (m < t) ? expf(sc - mx) : 0.f;
            float sum = e;
            for (int off = 1; off < 64; off <<= 1) sum += __shfl_xor(sum, off);
            float w2 = e / sum;
            if (m < t) wl[rw][t * 33 + m] = w2;
            float p = (m < t) ? w2 * sigf(sc * cg + cb) : 0.f;
            for (int off = 1; off < 64; off <<= 1) p += __shfl_xor(p, off);
            if (l == 0) wl[rw][t] = p;            // wc in row 0
        }
        __syncthreads();
    }

    // ---- persistent pointers / constants for the gates phase
    const int mt = my * 2 + wm;
    const ushort* Bb[5];
#pragma unroll
    for (int ti = 0; ti < 5; ti++) {
        int T = (ti < 4) ? (wn * 4 + ti) : 8;
        Bb[ti] = Wpk + (size_t)(G * 9 + T) * 25600 + l * 8;
    }
    const float bi  = biasPk[(G * 9 + wn * 4 + 0) * 16 + c16];
    const float bf_ = biasPk[(G * 9 + wn * 4 + 1) * 16 + c16];
    const float bg  = biasPk[(G * 9 + wn * 4 + 2) * 16 + c16];
    const float bo  = biasPk[(G * 9 + wn * 4 + 3) * 16 + c16];
    const float bk  = biasPk[(G * 9 + 8) * 16 + c16];
    const int crow = (l >> 4) << 2;
    const int row0e = my * 32 + wm * 16 + crow;
    const int u = G * 32 + wn * 16 + c16;
    const int kku = HOFF + u, shu = kku >> 5, kinu = kku & 31;
    const int lgrp = (kinu >> 3) << 4, eu = kinu & 7;

    float cc[4] = {0.f, 0.f, 0.f, 0.f};       // c-state lives in registers

    for (int t = 0; t <= 32; t++) {
        const ushort* inC = (t & 1) ? buf1 : buf0;
        ushort* inN = (t & 1) ? buf0 : buf1;
        const ushort* Ab = inC + (size_t)mt * 25600 + l * 8;

        f32x4 acc[5];
#pragma unroll
        for (int i = 0; i < 5; i++) acc[i] = (f32x4){0.f, 0.f, 0.f, 0.f};

        bf16x8 a_[3][2], b_[3][5][2];
        auto LD = [&](int s, int ph) {
            a_[ph][0] = *(const bf16x8*)(Ab + (s * 2 + 0) * 512);
            a_[ph][1] = *(const bf16x8*)(Ab + (s * 2 + 1) * 512);
#pragma unroll
            for (int ti = 0; ti < 5; ti++) {
                b_[ph][ti][0] = *(const bf16x8*)(Bb[ti] + (s * 2 + 0) * 512);
                b_[ph][ti][1] = *(const bf16x8*)(Bb[ti] + (s * 2 + 1) * 512);
            }
        };
        LD(0, 0); LD(1, 1);
#pragma unroll
        for (int s = 0; s < 25; s++) {
            const int ph = s % 3;
            if (s + 2 < 25) LD(s + 2, (s + 2) % 3);
            const bf16x8 ah = a_[ph][0], al = a_[ph][1];
#pragma unroll
            for (int ti = 0; ti < 5; ti++) {
                acc[ti] = __builtin_amdgcn_mfma_f32_16x16x32_bf16(ah, b_[ph][ti][0], acc[ti], 0, 0, 0);
                acc[ti] = __builtin_amdgcn_mfma_f32_16x16x32_bf16(ah, b_[ph][ti][1], acc[ti], 0, 0, 0);
                acc[ti] = __builtin_amdgcn_mfma_f32_16x16x32_bf16(al, b_[ph][ti][0], acc[ti], 0, 0, 0);
            }
        }

        // ---- LSTM cell epilogue (c in regs, h packed to next-step A)
#pragma unroll
        for (int rr = 0; rr < 4; rr++) {
            int row = row0e + rr;
            float ig = sigf(acc[0][rr] + bi), fg = sigf(acc[1][rr] + bf_);
            float gg = tanhf(acc[2][rr] + bg), og = sigf(acc[3][rr] + bo);
            float cn = fg * cc[rr] + ig * gg;
            float hv = og * tanhf(cn);
            cc[rr] = cn;
            size_t o0 = ((size_t)((row >> 4) * 25 + shu) * 2) * 512 + (lgrp | (row & 15)) * 8 + eu;
            inN[o0]       = f2hi(hv);
            inN[o0 + 512] = f2lo(hv);
        }
        if (wn == 1 && t >= 1) {
            int kc = G * 16 + c16;
#pragma unroll
            for (int rr = 0; rr < 4; rr++) {
                int row = row0e + rr;
                float v = fmaxf(acc[4][rr] + bk, 0.f);
                Mk[((size_t)(t - 1) * BATCH + row) * KS + kc] = v;
            }
        }

        gbar(bar);

        if (t >= 1 && t <= 31) {
            // ---- post: key_r(t+1) for rows 2*flat, 2*flat+1
            for (int rr2 = 0; rr2 < 2; rr2++) {
                int b = flat * 2 + rr2;
                int mtb = b >> 4, bl15 = b & 15;
                float hsum = 0.f;
#pragma unroll
                for (int q = 0; q < 2; q++) {
                    int j = tid + q * 256;
                    int kk = HOFF + j, sh = kk >> 5, kin = kk & 31;
                    size_t o = ((size_t)(mtb * 25 + sh) * 2) * 512 + (((kin >> 3) << 4) | bl15) * 8 + (kin & 7);
                    float hv = bf2f(inN[o]) + bf2f(inN[o + 512]);
                    hsum += hv * W_g[j];
                }
                red[tid] = hsum;
                __syncthreads();
                for (int s2 = 128; s2 > 0; s2 >>= 1) {
                    if (tid < s2) red[tid] += red[tid + s2];
                    __syncthreads();
                }
                if (tid == 0) gsh = sigf(red[0] + b_g[0]);
                __syncthreads();
                float g = gsh;
                float acc2 = 0.f;
                for (int m = 0; m < t; m++)
                    acc2 += wl[rr2][t * 33 + m] * Mk[((size_t)m * BATCH + b) * KS + tid];
                float v = g * acc2;
                int sh2 = tid >> 5, kin2 = tid & 31;
                size_t o2 = ((size_t)(mtb * 25 + sh2) * 2) * 512 + (((kin2 >> 3) << 4) | bl15) * 8 + (kin2 & 7);
                inN[o2]       = f2hi(v);
                inN[o2 + 512] = f2lo(v);
                if (tid == 0) {
                    float vc = g * wl[rr2][t];
                    size_t o3 = ((size_t)(mtb * 25 + 8) * 2) * 512 + bl15 * 8;
                    inN[o3]       = f2hi(vc);
                    inN[o3 + 512] = f2lo(vc);
                }
                __syncthreads();
            }
            gbar(bar);
        }
    }

    // ---- y + argmax: h(32) lives in buf1
    if (w < 2) {
        int b = flat * 2 + w;
        int mtb = b >> 4, bl15 = b & 15;
        float a0 = 0, a1 = 0, a2 = 0, a3 = 0;
        for (int r = 0; r < 8; r++) {
            int j = l + r * 64;
            int kk = HOFF + j, sh = kk >> 5, kin = kk & 31;
            size_t o = ((size_t)(mtb * 25 + sh) * 2) * 512 + (((kin >> 3) << 4) | bl15) * 8 + (kin & 7);
            float hv = bf2f(buf1[o]) + bf2f(buf1[o + 512]);
            a0 += hv * W_y[j];
            a1 += hv * W_y[512 + j];
            a2 += hv * W_y[1024 + j];
            a3 += hv * W_y[1536 + j];
        }
        for (int off = 32; off > 0; off >>= 1) {
            a0 += __shfl_xor(a0, off);
            a1 += __shfl_xor(a1, off);
            a2 += __shfl_xor(a2, off);
            a3 += __shfl_xor(a3, off);
        }
        if (l == 0) {
            float y0 = a0 + b_y[0], y1 = a1 + b_y[1], y2 = a2 + b_y[2], y3 = a3 + b_y[3];
            out[b * 4 + 0] = y0; out[b * 4 + 1] = y1; out[b * 4 + 2] = y2; out[b * 4 + 3] = y3;
            int best = 0; float bv = y0;
            if (y1 > bv) { bv = y1; best = 1; }
            if (y2 > bv) { bv = y2; best = 2; }
            if (y3 > bv) { bv = y3; best = 3; }
            out[2048 + b] = (float)best;
        }
    }
}

// ---------------------------------------------------------------------------
extern "C" void kernel_launch(void* const* d_in, const int* in_sizes, int n_in,
                              void* d_out, int out_size, void* d_ws, size_t ws_size,
                              hipStream_t stream)
{
    const float* x_seq = (const float*)d_in[0];
    const float* W_enc = (const float*)d_in[1];
    const float* gamma = (const float*)d_in[2];
    const float* beta  = (const float*)d_in[3];
    const float* W_ih  = (const float*)d_in[4];
    const float* W_hh  = (const float*)d_in[5];
    const float* b_ih  = (const float*)d_in[6];
    const float* b_hh  = (const float*)d_in[7];
    const float* W_key = (const float*)d_in[8];
    const float* b_key = (const float*)d_in[9];
    const float* W_g   = (const float*)d_in[10];
    const float* b_g   = (const float*)d_in[11];
    const float* cgain = (const float*)d_in[12];
    const float* cbias = (const float*)d_in[13];
    const float* W_y   = (const float*)d_in[14];
    const float* b_y   = (const float*)d_in[15];

    float* ws     = (float*)d_ws;
    float* z_pad  = ws;                          // 2,162,688 f
    float* Mk     = z_pad + 2162688;             // 4,194,304 f
    float* biasPk = Mk + 4194304;                // 2,304 f
    uint*  bar    = (uint*)(biasPk + 2304);      // 8 u
    ushort* inPk0 = (ushort*)(bar + 8);          // 819,200 us
    ushort* inPk1 = inPk0 + APK;                 // 819,200 us
    ushort* Wpk   = inPk1 + APK;                 // 3,686,400 us
    ushort* Epk   = Wpk + GP;                    // 262,144 us

    // zero barrier counter + both packed input buffers (covers t=0 zero-A,
    // zero key_r(0/1), and all pad columns)
    hipMemsetAsync(bar, 0, 8 * sizeof(uint) + 2 * APK * sizeof(ushort), stream);

    prep_w<<<(GP + EP + 2304 + 255) / 256, 256, 0, stream>>>(
        W_ih, W_hh, W_key, b_ih, b_hh, b_key, W_enc, Wpk, Epk, biasPk);

    enc_k<<<512, 256, 0, stream>>>(x_seq, Epk, z_pad);

    loop_k<<<NBLK, 256, 0, stream>>>(
        z_pad, Wpk, biasPk, Mk, inPk0, inPk1,
        W_g, b_g, cgain, cbias, W_y, b_y, gamma, beta,
        (float*)d_out, bar);
}